// Round 4
// baseline (280.291 us; speedup 1.0000x reference)
//
#include <hip/hip_runtime.h>
#include <stdint.h>
#include <stddef.h>

// Problem constants
#define BB 8
#define CC 16
#define DD 192
#define OCC 4
#define OHH 50
#define OWW 200

#define LDP 200   // padded LDS row stride in bf16 elements (192 + 8)
#define CH  24    // 8-element chunks per 192 row

typedef __attribute__((ext_vector_type(8))) short s8v;   // 8 bf16 = 16B (MFMA A/B frag)
typedef __attribute__((ext_vector_type(4))) short s4v;   // 4 bf16 = 8B
typedef __attribute__((ext_vector_type(4))) float f4v;   // 4 fp32
typedef __attribute__((ext_vector_type(4))) float f32x4; // MFMA C/D frag

__device__ __forceinline__ short rne_bf16(float f) {
  uint32_t u = __float_as_uint(f);
  u += 0x7fffu + ((u >> 16) & 1u);
  return (short)(u >> 16);
}
__device__ __forceinline__ float bf2f(short s) {
  return __uint_as_float(((uint32_t)(uint16_t)s) << 16);
}

// ---------------- prep_all: R-cvt | P-cvt | x-transpose | PT-transpose ----------------
#define PREP_R_BLK 9216
#define PREP_P_BLK 600
#define PREP_X_BLK 4608
#define PREP_PT_BLK 2688
#define PREP_TOTAL (PREP_R_BLK + PREP_P_BLK + PREP_X_BLK + PREP_PT_BLK)

__global__ __launch_bounds__(256) void prep_all(const float* __restrict__ R, short* __restrict__ Rb,
                                                const float* __restrict__ P, short* __restrict__ Pb,
                                                const float* __restrict__ x, short* __restrict__ XTb,
                                                const float* __restrict__ PT, short* __restrict__ PTTb) {
  __shared__ float tile[32][33];
  const int blk = blockIdx.x;
  const int tid = threadIdx.x;

  if (blk < PREP_R_BLK) {
    int idx = blk * 256 + tid;
    f4v v = *(const f4v*)(R + (size_t)idx * 4);
    s4v o;
    #pragma unroll
    for (int r = 0; r < 4; ++r) o[r] = rne_bf16(v[r]);
    *(s4v*)(Rb + (size_t)idx * 4) = o;
    return;
  }
  if (blk < PREP_R_BLK + PREP_P_BLK) {
    int idx = (blk - PREP_R_BLK) * 256 + tid;
    f4v v = *(const f4v*)(P + (size_t)idx * 4);
    s4v o;
    #pragma unroll
    for (int r = 0; r < 4; ++r) o[r] = rne_bf16(v[r]);
    *(s4v*)(Pb + (size_t)idx * 4) = o;
    return;
  }
  const int tx = tid & 31, ty = tid >> 5;
  if (blk < PREP_R_BLK + PREP_P_BLK + PREP_X_BLK) {
    int t = blk - (PREP_R_BLK + PREP_P_BLK);
    int outer = t / 36, rem = t % 36;
    int p0 = (rem / 6) * 32, q0 = (rem % 6) * 32;
    const float* src = x + (size_t)outer * DD * DD;
    for (int r = ty; r < 32; r += 8)
      tile[r][tx] = src[(size_t)(p0 + r) * DD + q0 + tx];
    __syncthreads();
    short* dst = XTb + (size_t)outer * DD * DD;
    for (int r = ty; r < 32; r += 8)
      dst[(size_t)(q0 + r) * DD + p0 + tx] = rne_bf16(tile[tx][r]);
    return;
  }
  {
    int t = blk - (PREP_R_BLK + PREP_P_BLK + PREP_X_BLK);
    int outer = t / 42, rem = t % 42;
    int q0 = (rem / 7) * 32, n0 = (rem % 7) * 32;
    const float* src = PT + (size_t)outer * DD * OWW;
    for (int r = ty; r < 32; r += 8)
      tile[r][tx] = (n0 + tx < OWW) ? src[(size_t)(q0 + r) * OWW + n0 + tx] : 0.f;
    __syncthreads();
    short* dst = PTTb + (size_t)outer * OWW * DD;
    for (int r = ty; r < 32; r += 8)
      if (n0 + r < OWW) dst[(size_t)(n0 + r) * DD + q0 + tx] = rne_bf16(tile[tx][r]);
  }
}

// ---------------- stage A ----------------
// Register prefetch of next j's tiles overlaps mm2. LDS 153.6 KB -> 1 block/CU
// regardless of VGPRs, so __launch_bounds__(512,1): allocator may use up to 256
// VGPR/thread (the (512,2) cap of 128 caused scratch spills in R3).
__global__ __launch_bounds__(512, 1) void stageA(const short* __restrict__ Rb,
                                                 const short* __restrict__ XTb,
                                                 short* __restrict__ ypart) {
  __shared__ __align__(16) short ldsR[DD * LDP];
  __shared__ __align__(16) short lds2[DD * LDP];
  const int tid = threadIdx.x;
  const int bx = blockIdx.x;
  const int b = bx >> 5, i = (bx >> 1) & 15, jg = bx & 1;
  const int lane15 = tid & 15, quad = (tid & 63) >> 4;
  const int wid = tid >> 6;
  const int wm = wid & 3;   // B-operand dim: 3 tiles each
  const int wq = wid >> 2;  // A-operand dim: 6 tiles each

  int ldsoff[9];
  #pragma unroll
  for (int it = 0; it < 9; ++it) {
    int c = tid + it * 512;
    ldsoff[it] = (c / CH) * LDP + (c % CH) * 8;
  }

  f32x4 acc_y[6][3];
  #pragma unroll
  for (int a = 0; a < 6; ++a)
    #pragma unroll
    for (int c = 0; c < 3; ++c) acc_y[a][c] = (f32x4){0.f, 0.f, 0.f, 0.f};

  s8v preR[9], preX[9];
  {
    const short* sR = Rb + (size_t)(i * CC + jg * 8) * (DD * DD);
    const short* sX = XTb + (size_t)(b * CC + jg * 8) * (DD * DD);
    #pragma unroll
    for (int it = 0; it < 9; ++it) {
      preR[it] = *(const s8v*)(sR + (size_t)tid * 8 + (size_t)it * 4096);
      preX[it] = *(const s8v*)(sX + (size_t)tid * 8 + (size_t)it * 4096);
    }
  }

  for (int jj = 0; jj < 8; ++jj) {
    __syncthreads();
    #pragma unroll
    for (int it = 0; it < 9; ++it) {
      *(s8v*)(&ldsR[ldsoff[it]]) = preR[it];
      *(s8v*)(&lds2[ldsoff[it]]) = preX[it];
    }
    __syncthreads();

    // mm1: T^T = XT rows x R rows
    f32x4 acc_t[6][3];
    #pragma unroll
    for (int a = 0; a < 6; ++a)
      #pragma unroll
      for (int c = 0; c < 3; ++c) acc_t[a][c] = (f32x4){0.f, 0.f, 0.f, 0.f};

    #pragma unroll
    for (int kc = 0; kc < 6; ++kc) {
      s8v af[6], bf[3];
      #pragma unroll
      for (int a = 0; a < 6; ++a)
        af[a] = *(const s8v*)(&lds2[((wq * 6 + a) * 16 + lane15) * LDP + kc * 32 + quad * 8]);
      #pragma unroll
      for (int c = 0; c < 3; ++c)
        bf[c] = *(const s8v*)(&ldsR[((wm * 3 + c) * 16 + lane15) * LDP + kc * 32 + quad * 8]);
      #pragma unroll
      for (int a = 0; a < 6; ++a)
        #pragma unroll
        for (int c = 0; c < 3; ++c)
          acc_t[a][c] = __builtin_amdgcn_mfma_f32_16x16x32_bf16(af[a], bf[c], acc_t[a][c], 0, 0, 0);
    }
    __syncthreads();

    // pack T[m][q] into lds2
    #pragma unroll
    for (int a = 0; a < 6; ++a) {
      #pragma unroll
      for (int c = 0; c < 3; ++c) {
        s4v pk;
        #pragma unroll
        for (int r = 0; r < 4; ++r) pk[r] = rne_bf16(acc_t[a][c][r]);
        int m = (wm * 3 + c) * 16 + lane15;
        int q0 = (wq * 6 + a) * 16 + quad * 4;
        *(s4v*)(&lds2[m * LDP + q0]) = pk;
      }
    }
    __syncthreads();

    // prefetch next j during mm2 (acc_t dead)
    if (jj < 7) {
      const short* sR = Rb + (size_t)(i * CC + jg * 8 + jj + 1) * (DD * DD);
      const short* sX = XTb + (size_t)(b * CC + jg * 8 + jj + 1) * (DD * DD);
      #pragma unroll
      for (int it = 0; it < 9; ++it) {
        preR[it] = *(const s8v*)(sR + (size_t)tid * 8 + (size_t)it * 4096);
        preX[it] = *(const s8v*)(sX + (size_t)tid * 8 + (size_t)it * 4096);
      }
    }

    // mm2: y = T rows x R rows
    #pragma unroll
    for (int kc = 0; kc < 6; ++kc) {
      s8v af[6], bf[3];
      #pragma unroll
      for (int a = 0; a < 6; ++a)
        af[a] = *(const s8v*)(&lds2[((wq * 6 + a) * 16 + lane15) * LDP + kc * 32 + quad * 8]);
      #pragma unroll
      for (int c = 0; c < 3; ++c)
        bf[c] = *(const s8v*)(&ldsR[((wm * 3 + c) * 16 + lane15) * LDP + kc * 32 + quad * 8]);
      #pragma unroll
      for (int a = 0; a < 6; ++a)
        #pragma unroll
        for (int c = 0; c < 3; ++c)
          acc_y[a][c] = __builtin_amdgcn_mfma_f32_16x16x32_bf16(af[a], bf[c], acc_y[a][c], 0, 0, 0);
    }
  }

  // pack y^T [n][m] into lds2, coalesced store
  __syncthreads();
  #pragma unroll
  for (int a = 0; a < 6; ++a) {
    #pragma unroll
    for (int c = 0; c < 3; ++c) {
      s4v pk;
      #pragma unroll
      for (int r = 0; r < 4; ++r) pk[r] = rne_bf16(acc_y[a][c][r]);
      int n = (wm * 3 + c) * 16 + lane15;
      int m0 = (wq * 6 + a) * 16 + quad * 4;
      *(s4v*)(&lds2[n * LDP + m0]) = pk;
    }
  }
  __syncthreads();
  {
    short* dst = ypart + (size_t)(jg * (BB * CC) + b * CC + i) * (DD * DD);
    #pragma unroll
    for (int it = 0; it < 9; ++it) {
      int c = tid + it * 512;
      *(s8v*)(dst + (size_t)c * 8) = *(const s8v*)(&lds2[ldsoff[it]]);
    }
  }
}

// ---------------- stage B1 ----------------
// U[b,j] = P_cat[:,j] @ y[b,j]  for all 4 oc at once; U stored [200(m_cat)][192(q)] bf16.
// Block = (b,j) -> 128 blocks, 512 threads, ONE barrier. Reads y[b,j] exactly once
// (sum of the two jg ypart halves fused into staging).
// A = yT rows (q), B = P_cat rows (m_cat); C[q][m] -> per-lane s4v = U[m][q0..3].
__global__ __launch_bounds__(512, 1) void stageB1(const short* __restrict__ ypart,
                                                  const short* __restrict__ Pb,
                                                  short* __restrict__ U) {
  __shared__ __align__(16) short ldsYT[DD * LDP];    // 76800 B
  __shared__ __align__(16) short ldsP[208 * LDP];    // 83200 B (rows 200..207 zero)
  const int tid = threadIdx.x;
  const int bx = blockIdx.x;
  const int b = bx >> 4, j = bx & 15;
  const int lane15 = tid & 15, quad = (tid & 63) >> 4;
  const int wid = tid >> 6;
  const int wq1 = wid >> 1;  // 0..3 -> 3 q-tiles each (12 total)
  const int wm1 = wid & 1;   // 0..1 -> tiles wm1*7 .. (7 or 6 of 13 total)

  {
    const short* p0 = ypart + (size_t)(b * CC + j) * (DD * DD);
    const short* p1 = p0 + (size_t)(BB * CC) * (DD * DD);
    for (int c = tid; c < DD * CH; c += 512) {
      s8v v0 = *(const s8v*)(p0 + (size_t)c * 8);
      s8v v1 = *(const s8v*)(p1 + (size_t)c * 8);
      s8v o;
      #pragma unroll
      for (int r = 0; r < 8; ++r) o[r] = rne_bf16(bf2f(v0[r]) + bf2f(v1[r]));
      *(s8v*)(&ldsYT[(c / CH) * LDP + (c % CH) * 8]) = o;
    }
    const s8v z = {0, 0, 0, 0, 0, 0, 0, 0};
    for (int c = tid; c < 208 * CH; c += 512) {
      int row = c / CH, col = c % CH;
      s8v v = z;
      if (row < 200) {
        int oc = row / 50, m = row - oc * 50;
        v = *(const s8v*)(Pb + (size_t)(oc * CC + j) * (OHH * DD) + (size_t)m * DD + col * 8);
      }
      *(s8v*)(&ldsP[row * LDP + col * 8]) = v;
    }
  }
  __syncthreads();

  f32x4 acc[3][7];
  #pragma unroll
  for (int a = 0; a < 3; ++a)
    #pragma unroll
    for (int c = 0; c < 7; ++c) acc[a][c] = (f32x4){0.f, 0.f, 0.f, 0.f};

  #pragma unroll
  for (int kc = 0; kc < 6; ++kc) {
    s8v af[3], bf[7];
    #pragma unroll
    for (int a = 0; a < 3; ++a)
      af[a] = *(const s8v*)(&ldsYT[((wq1 * 3 + a) * 16 + lane15) * LDP + kc * 32 + quad * 8]);
    #pragma unroll
    for (int c = 0; c < 7; ++c) {
      int tn = wm1 * 7 + c;
      if (tn < 13)
        bf[c] = *(const s8v*)(&ldsP[(tn * 16 + lane15) * LDP + kc * 32 + quad * 8]);
    }
    #pragma unroll
    for (int a = 0; a < 3; ++a)
      #pragma unroll
      for (int c = 0; c < 7; ++c)
        if (wm1 * 7 + c < 13)
          acc[a][c] = __builtin_amdgcn_mfma_f32_16x16x32_bf16(af[a], bf[c], acc[a][c], 0, 0, 0);
  }

  // store U[m_cat][q] (bf16), skip pad rows
  short* ub = U + (size_t)bx * (200 * DD);
  #pragma unroll
  for (int a = 0; a < 3; ++a) {
    #pragma unroll
    for (int c = 0; c < 7; ++c) {
      int tn = wm1 * 7 + c;
      if (tn < 13) {
        int m = tn * 16 + lane15;
        if (m < 200) {
          s4v pk;
          #pragma unroll
          for (int r = 0; r < 4; ++r) pk[r] = rne_bf16(acc[a][c][r]);
          int q0 = (wq1 * 3 + a) * 16 + quad * 4;
          *(s4v*)(ub + (size_t)m * DD + q0) = pk;
        }
      }
    }
  }
}

// ---------------- stage B2 ----------------
// out[b,oc][m][n] += sum_j U[b,j][oc*50+m][q] PT[oc,j][q][n]
// Block = (b, oc, nq in 4, jg in 4) -> 512 blocks, 256 threads, 4 j each.
// LDS 51.2 KB -> 2 resident blocks/CU for stage/compute overlap.
__global__ __launch_bounds__(256, 2) void stageB2(const short* __restrict__ U,
                                                  const short* __restrict__ PTTb,
                                                  float* __restrict__ out) {
  __shared__ __align__(16) short ldsU[64 * LDP];
  __shared__ __align__(16) short ldsPT[64 * LDP];
  const int tid = threadIdx.x;
  const int bx = blockIdx.x;
  const int jg = bx & 3, nq = (bx >> 2) & 3, oc = (bx >> 4) & 3, b = bx >> 6;
  const int lane15 = tid & 15, quad = (tid & 63) >> 4;
  const int wid = tid >> 6;
  const int wm2 = wid & 1, wn2 = wid >> 1;

  f32x4 acc[2][2];
  #pragma unroll
  for (int a = 0; a < 2; ++a)
    #pragma unroll
    for (int e = 0; e < 2; ++e) acc[a][e] = (f32x4){0.f, 0.f, 0.f, 0.f};

  const s8v z = {0, 0, 0, 0, 0, 0, 0, 0};
  for (int jj = 0; jj < 4; ++jj) {
    const int j = jg * 4 + jj;
    __syncthreads();
    {
      const short* us = U + (size_t)((b * CC + j) * 200 + oc * 50) * DD;
      const short* ps = PTTb + (size_t)(oc * CC + j) * (OWW * DD) + (size_t)(nq * 50) * DD;
      for (int c = tid; c < 64 * CH; c += 256) {
        int row = c / CH, col = c % CH;
        s8v vu = (row < 50) ? *(const s8v*)(us + (size_t)row * DD + col * 8) : z;
        s8v vp = (row < 50) ? *(const s8v*)(ps + (size_t)row * DD + col * 8) : z;
        *(s8v*)(&ldsU[row * LDP + col * 8]) = vu;
        *(s8v*)(&ldsPT[row * LDP + col * 8]) = vp;
      }
    }
    __syncthreads();

    #pragma unroll
    for (int kc = 0; kc < 6; ++kc) {
      s8v af[2], bf[2];
      #pragma unroll
      for (int a = 0; a < 2; ++a)
        af[a] = *(const s8v*)(&ldsU[((wm2 * 2 + a) * 16 + lane15) * LDP + kc * 32 + quad * 8]);
      #pragma unroll
      for (int e = 0; e < 2; ++e)
        bf[e] = *(const s8v*)(&ldsPT[((wn2 * 2 + e) * 16 + lane15) * LDP + kc * 32 + quad * 8]);
      #pragma unroll
      for (int a = 0; a < 2; ++a)
        #pragma unroll
        for (int e = 0; e < 2; ++e)
          acc[a][e] = __builtin_amdgcn_mfma_f32_16x16x32_bf16(af[a], bf[e], acc[a][e], 0, 0, 0);
    }
  }

  float* dst = out + (size_t)(b * OCC + oc) * (OHH * OWW);
  #pragma unroll
  for (int a = 0; a < 2; ++a) {
    #pragma unroll
    for (int e = 0; e < 2; ++e) {
      int n = (wn2 * 2 + e) * 16 + lane15;
      if (n < 50) {
        #pragma unroll
        for (int r = 0; r < 4; ++r) {
          int m = (wm2 * 2 + a) * 16 + quad * 4 + r;
          if (m < OHH)
            atomicAdd(&dst[(size_t)m * OWW + nq * 50 + n], acc[a][e][r]);
        }
      }
    }
  }
}

// ---------------- launcher ----------------

extern "C" void kernel_launch(void* const* d_in, const int* in_sizes, int n_in,
                              void* d_out, int out_size, void* d_ws, size_t ws_size,
                              hipStream_t stream) {
  const float* x  = (const float*)d_in[0];
  const float* R  = (const float*)d_in[1];
  const float* P  = (const float*)d_in[2];
  const float* PT = (const float*)d_in[3];
  float* out = (float*)d_out;

  short* W = (short*)d_ws;
  const size_t nR   = (size_t)CC * CC * DD * DD;     // 9,437,184
  const size_t nX   = (size_t)BB * CC * DD * DD;     // 4,718,592
  const size_t nP   = (size_t)OCC * CC * OHH * DD;   // 614,400
  const size_t nPT  = (size_t)OCC * CC * OWW * DD;   // 2,457,600
  short* Rb    = W;
  short* XTb   = Rb + nR;
  short* Pb    = XTb + nX;
  short* PTTb  = Pb + nP;
  short* ypart = PTTb + nPT;                          // 2 * nX
  short* Ubuf  = ypart + 2 * nX;                      // 128 * 200 * 192 = 4,915,200

  prep_all<<<PREP_TOTAL, 256, 0, stream>>>(R, Rb, P, Pb, x, XTb, PT, PTTb);
  hipMemsetAsync(d_out, 0, (size_t)out_size * sizeof(float), stream);
  stageA<<<BB * CC * 2, 512, 0, stream>>>(Rb, XTb, ypart);
  stageB1<<<BB * CC, 512, 0, stream>>>(ypart, Pb, Ubuf);
  stageB2<<<BB * OCC * 4 * 4, 256, 0, stream>>>(Ubuf, PTTb, out);
}

// Round 5
// 237.547 us; speedup vs baseline: 1.1799x; 1.1799x over previous
//
#include <hip/hip_runtime.h>
#include <stdint.h>
#include <stddef.h>

// Problem constants
#define BB 8
#define CC 16
#define DD 192
#define OCC 4
#define OHH 50
#define OWW 200

#define LDP 200   // padded LDS row stride in bf16 elements (192 + 8)
#define CH  24    // 8-element chunks per 192 row

typedef __attribute__((ext_vector_type(8))) short s8v;   // 8 bf16 = 16B (MFMA A/B frag)
typedef __attribute__((ext_vector_type(4))) short s4v;   // 4 bf16 = 8B
typedef __attribute__((ext_vector_type(4))) float f4v;   // 4 fp32
typedef __attribute__((ext_vector_type(4))) float f32x4; // MFMA C/D frag

__device__ __forceinline__ short rne_bf16(float f) {
  uint32_t u = __float_as_uint(f);
  u += 0x7fffu + ((u >> 16) & 1u);
  return (short)(u >> 16);
}
__device__ __forceinline__ float bf2f(short s) {
  return __uint_as_float(((uint32_t)(uint16_t)s) << 16);
}

// async 16B-per-lane global->LDS DMA (no VGPR round trip)
__device__ __forceinline__ void async_copy16(short* lds_dst, const short* g_src) {
  __builtin_amdgcn_global_load_lds(
      (const __attribute__((address_space(1))) void*)g_src,
      (__attribute__((address_space(3))) void*)lds_dst, 16, 0, 0);
}

// ---------------- prep_all: R-cvt | P-cvt | x-transpose(padded out) | PT-transpose ----------------
#define PREP_R_BLK 9216
#define PREP_P_BLK 600
#define PREP_X_BLK 4608
#define PREP_PT_BLK 2688
#define PREP_TOTAL (PREP_R_BLK + PREP_P_BLK + PREP_X_BLK + PREP_PT_BLK)

__global__ __launch_bounds__(256) void prep_all(const float* __restrict__ R, short* __restrict__ Rb,
                                                const float* __restrict__ P, short* __restrict__ Pb,
                                                const float* __restrict__ x, short* __restrict__ XTb,
                                                const float* __restrict__ PT, short* __restrict__ PTTb) {
  __shared__ float tile[32][33];
  const int blk = blockIdx.x;
  const int tid = threadIdx.x;

  if (blk < PREP_R_BLK) {
    int idx = blk * 256 + tid;
    f4v v = *(const f4v*)(R + (size_t)idx * 4);
    s4v o;
    #pragma unroll
    for (int r = 0; r < 4; ++r) o[r] = rne_bf16(v[r]);
    *(s4v*)(Rb + (size_t)idx * 4) = o;
    return;
  }
  if (blk < PREP_R_BLK + PREP_P_BLK) {
    int idx = (blk - PREP_R_BLK) * 256 + tid;
    f4v v = *(const f4v*)(P + (size_t)idx * 4);
    s4v o;
    #pragma unroll
    for (int r = 0; r < 4; ++r) o[r] = rne_bf16(v[r]);
    *(s4v*)(Pb + (size_t)idx * 4) = o;
    return;
  }
  const int tx = tid & 31, ty = tid >> 5;
  if (blk < PREP_R_BLK + PREP_P_BLK + PREP_X_BLK) {
    // XTb padded: [outer][q][p] with row stride LDP (pad cols 192..199 garbage)
    int t = blk - (PREP_R_BLK + PREP_P_BLK);
    int outer = t / 36, rem = t % 36;
    int p0 = (rem / 6) * 32, q0 = (rem % 6) * 32;
    const float* src = x + (size_t)outer * DD * DD;
    for (int r = ty; r < 32; r += 8)
      tile[r][tx] = src[(size_t)(p0 + r) * DD + q0 + tx];
    __syncthreads();
    short* dst = XTb + (size_t)outer * DD * LDP;
    for (int r = ty; r < 32; r += 8)
      dst[(size_t)(q0 + r) * LDP + p0 + tx] = rne_bf16(tile[tx][r]);
    return;
  }
  {
    int t = blk - (PREP_R_BLK + PREP_P_BLK + PREP_X_BLK);
    int outer = t / 42, rem = t % 42;
    int q0 = (rem / 7) * 32, n0 = (rem % 7) * 32;
    const float* src = PT + (size_t)outer * DD * OWW;
    for (int r = ty; r < 32; r += 8)
      tile[r][tx] = (n0 + tx < OWW) ? src[(size_t)(q0 + r) * OWW + n0 + tx] : 0.f;
    __syncthreads();
    short* dst = PTTb + (size_t)outer * OWW * DD;
    for (int r = ty; r < 32; r += 8)
      if (n0 + r < OWW) dst[(size_t)(n0 + r) * DD + q0 + tx] = rne_bf16(tile[tx][r]);
  }
}

// ---------------- stage A ----------------
// y[b,i] = sum_j R[i,j] @ x[b,j] @ R[i,j]^T, split over jg halves.
// B-operand (R) frags read DIRECTLY from global (L2); LDS holds X^T (DMA'd, padded)
// and a dedicated T buffer. 2 barriers per j; X[j+1] DMA overlaps mm2[j].
__global__ __launch_bounds__(512, 1) void stageA(const short* __restrict__ Rb,
                                                 const short* __restrict__ XTb,
                                                 short* __restrict__ ypart) {
  __shared__ __align__(16) short ldsX[DD * LDP];  // 76.8 KB, DMA target (padded tile)
  __shared__ __align__(16) short ldsT[DD * LDP];  // 76.8 KB
  const int tid = threadIdx.x;
  const int bx = blockIdx.x;
  const int b = bx >> 5, i = (bx >> 1) & 15, jg = bx & 1;
  const int lane15 = tid & 15, quad = (tid & 63) >> 4;
  const int wid = tid >> 6;
  const int wm = wid & 3;   // B-operand dim: 3 tiles each
  const int wq = wid >> 2;  // A-operand dim: 6 tiles each

  const short* xbase = XTb + (size_t)(b * CC + jg * 8) * (DD * LDP);

  // initial DMA of X^T[j0] (4800 16B chunks, linear copy of padded tile)
  #pragma unroll
  for (int it = 0; it < 10; ++it) {
    int c = tid + it * 512;
    if (c < DD * LDP / 8) async_copy16(&ldsX[c * 8], xbase + (size_t)c * 8);
  }

  f32x4 acc_y[6][3];
  #pragma unroll
  for (int a = 0; a < 6; ++a)
    #pragma unroll
    for (int c = 0; c < 3; ++c) acc_y[a][c] = (f32x4){0.f, 0.f, 0.f, 0.f};

  for (int jj = 0; jj < 8; ++jj) {
    const short* rbase = Rb + (size_t)(i * CC + jg * 8 + jj) * (DD * DD);
    __syncthreads();  // drains DMA; joins prev mm2 (ldsT readers)

    // mm1: T^T[q][m] = sum_p X^T[q][p] R[m][p]  (A = ldsX rows, B = global R rows)
    f32x4 acc_t[6][3];
    #pragma unroll
    for (int a = 0; a < 6; ++a)
      #pragma unroll
      for (int c = 0; c < 3; ++c) acc_t[a][c] = (f32x4){0.f, 0.f, 0.f, 0.f};

    #pragma unroll
    for (int kc = 0; kc < 6; ++kc) {
      s8v af[6], bf[3];
      #pragma unroll
      for (int a = 0; a < 6; ++a)
        af[a] = *(const s8v*)(&ldsX[((wq * 6 + a) * 16 + lane15) * LDP + kc * 32 + quad * 8]);
      #pragma unroll
      for (int c = 0; c < 3; ++c)
        bf[c] = *(const s8v*)(rbase + (size_t)((wm * 3 + c) * 16 + lane15) * DD + kc * 32 + quad * 8);
      #pragma unroll
      for (int a = 0; a < 6; ++a)
        #pragma unroll
        for (int c = 0; c < 3; ++c)
          acc_t[a][c] = __builtin_amdgcn_mfma_f32_16x16x32_bf16(af[a], bf[c], acc_t[a][c], 0, 0, 0);
    }

    // pack T[m][q] into ldsT (own buffer -> no barrier needed before writing)
    #pragma unroll
    for (int a = 0; a < 6; ++a) {
      #pragma unroll
      for (int c = 0; c < 3; ++c) {
        s4v pk;
        #pragma unroll
        for (int r = 0; r < 4; ++r) pk[r] = rne_bf16(acc_t[a][c][r]);
        int m = (wm * 3 + c) * 16 + lane15;
        int q0 = (wq * 6 + a) * 16 + quad * 4;
        *(s4v*)(&ldsT[m * LDP + q0]) = pk;
      }
    }
    __syncthreads();  // T complete; mm1's ldsX reads complete for ALL waves

    // async DMA of X^T[j+1] overlapping mm2 (writes ldsX, which mm2 never reads)
    if (jj < 7) {
      const short* xn = xbase + (size_t)(jj + 1) * (DD * LDP);
      #pragma unroll
      for (int it = 0; it < 10; ++it) {
        int c = tid + it * 512;
        if (c < DD * LDP / 8) async_copy16(&ldsX[c * 8], xn + (size_t)c * 8);
      }
    }

    // mm2: y[m][n] += T[m][q] R[n][q]  (A = ldsT rows, B = global R rows)
    #pragma unroll
    for (int kc = 0; kc < 6; ++kc) {
      s8v af[6], bf[3];
      #pragma unroll
      for (int a = 0; a < 6; ++a)
        af[a] = *(const s8v*)(&ldsT[((wq * 6 + a) * 16 + lane15) * LDP + kc * 32 + quad * 8]);
      #pragma unroll
      for (int c = 0; c < 3; ++c)
        bf[c] = *(const s8v*)(rbase + (size_t)((wm * 3 + c) * 16 + lane15) * DD + kc * 32 + quad * 8);
      #pragma unroll
      for (int a = 0; a < 6; ++a)
        #pragma unroll
        for (int c = 0; c < 3; ++c)
          acc_y[a][c] = __builtin_amdgcn_mfma_f32_16x16x32_bf16(af[a], bf[c], acc_y[a][c], 0, 0, 0);
    }
  }

  // pack y^T [n][m] into ldsX (not read since last mm1; no DMA pending), store
  __syncthreads();
  #pragma unroll
  for (int a = 0; a < 6; ++a) {
    #pragma unroll
    for (int c = 0; c < 3; ++c) {
      s4v pk;
      #pragma unroll
      for (int r = 0; r < 4; ++r) pk[r] = rne_bf16(acc_y[a][c][r]);
      int n = (wm * 3 + c) * 16 + lane15;   // y col
      int m0 = (wq * 6 + a) * 16 + quad * 4; // y row, 4 consecutive
      *(s4v*)(&ldsX[n * LDP + m0]) = pk;
    }
  }
  __syncthreads();
  {
    short* dst = ypart + (size_t)(jg * (BB * CC) + b * CC + i) * (DD * DD);
    for (int it = 0; it < 9; ++it) {
      int c = tid + it * 512;
      *(s8v*)(dst + (size_t)c * 8) = *(const s8v*)(&ldsX[(c / CH) * LDP + (c % CH) * 8]);
    }
  }
}

// ---------------- stage B1 ----------------
// U[b,j][m_cat][q] = sum_p P_cat[m_cat][p] y[b,j][p][q], split over q-halves.
// Block = (b, j, qh) -> 256 blocks, 512 threads, one barrier.
__global__ __launch_bounds__(512, 1) void stageB1(const short* __restrict__ ypart,
                                                  const short* __restrict__ Pb,
                                                  short* __restrict__ U) {
  __shared__ __align__(16) short ldsYT[96 * LDP];    // 38.4 KB (q-half rows)
  __shared__ __align__(16) short ldsP[208 * LDP];    // 83.2 KB (rows 200..207 zero)
  const int tid = threadIdx.x;
  const int bx = blockIdx.x;
  const int qh = bx & 1, j = (bx >> 1) & 15, b = bx >> 5;
  const int lane15 = tid & 15, quad = (tid & 63) >> 4;
  const int wid = tid >> 6;
  const int wq1 = wid >> 2;  // 0..1 -> 3 q-tiles each (6 in this half)
  const int wm1 = wid & 3;   // 0..3 -> 4 m_cat-tiles each (13 total, guarded)

  {
    const short* p0 = ypart + (size_t)(b * CC + j) * (DD * DD) + (size_t)(qh * 96) * DD;
    const short* p1 = p0 + (size_t)(BB * CC) * (DD * DD);
    for (int c = tid; c < 96 * CH; c += 512) {
      s8v v0 = *(const s8v*)(p0 + (size_t)c * 8);
      s8v v1 = *(const s8v*)(p1 + (size_t)c * 8);
      s8v o;
      #pragma unroll
      for (int r = 0; r < 8; ++r) o[r] = rne_bf16(bf2f(v0[r]) + bf2f(v1[r]));
      *(s8v*)(&ldsYT[(c / CH) * LDP + (c % CH) * 8]) = o;
    }
    const s8v z = {0, 0, 0, 0, 0, 0, 0, 0};
    for (int c = tid; c < 208 * CH; c += 512) {
      int row = c / CH, col = c % CH;
      s8v v = z;
      if (row < 200) {
        int oc = row / 50, m = row - oc * 50;
        v = *(const s8v*)(Pb + (size_t)(oc * CC + j) * (OHH * DD) + (size_t)m * DD + col * 8);
      }
      *(s8v*)(&ldsP[row * LDP + col * 8]) = v;
    }
  }
  __syncthreads();

  f32x4 acc[3][4];
  #pragma unroll
  for (int a = 0; a < 3; ++a)
    #pragma unroll
    for (int e = 0; e < 4; ++e) acc[a][e] = (f32x4){0.f, 0.f, 0.f, 0.f};

  #pragma unroll
  for (int kc = 0; kc < 6; ++kc) {
    s8v af[3], bf[4];
    #pragma unroll
    for (int a = 0; a < 3; ++a)
      af[a] = *(const s8v*)(&ldsYT[((wq1 * 3 + a) * 16 + lane15) * LDP + kc * 32 + quad * 8]);
    #pragma unroll
    for (int e = 0; e < 4; ++e) {
      int tn = wm1 * 4 + e;
      if (tn < 13)
        bf[e] = *(const s8v*)(&ldsP[(tn * 16 + lane15) * LDP + kc * 32 + quad * 8]);
    }
    #pragma unroll
    for (int a = 0; a < 3; ++a)
      #pragma unroll
      for (int e = 0; e < 4; ++e)
        if (wm1 * 4 + e < 13)
          acc[a][e] = __builtin_amdgcn_mfma_f32_16x16x32_bf16(af[a], bf[e], acc[a][e], 0, 0, 0);
  }

  // store U[m_cat][q] (bf16): col block qh*96 + tile*16 + quad*4
  short* ub = U + (size_t)(b * CC + j) * (200 * DD);
  #pragma unroll
  for (int a = 0; a < 3; ++a) {
    #pragma unroll
    for (int e = 0; e < 4; ++e) {
      int tn = wm1 * 4 + e;
      if (tn < 13) {
        int m = tn * 16 + lane15;
        if (m < 200) {
          s4v pk;
          #pragma unroll
          for (int r = 0; r < 4; ++r) pk[r] = rne_bf16(acc[a][e][r]);
          int q0 = qh * 96 + (wq1 * 3 + a) * 16 + quad * 4;
          *(s4v*)(ub + (size_t)m * DD + q0) = pk;
        }
      }
    }
  }
}

// ---------------- stage B2 ----------------
// out[b,oc][m][n] += sum_j U[b,j][oc*50+m][q] PT[oc,j][q][n]
__global__ __launch_bounds__(256, 2) void stageB2(const short* __restrict__ U,
                                                  const short* __restrict__ PTTb,
                                                  float* __restrict__ out) {
  __shared__ __align__(16) short ldsU[64 * LDP];
  __shared__ __align__(16) short ldsPT[64 * LDP];
  const int tid = threadIdx.x;
  const int bx = blockIdx.x;
  const int jg = bx & 3, nq = (bx >> 2) & 3, oc = (bx >> 4) & 3, b = bx >> 6;
  const int lane15 = tid & 15, quad = (tid & 63) >> 4;
  const int wid = tid >> 6;
  const int wm2 = wid & 1, wn2 = wid >> 1;

  f32x4 acc[2][2];
  #pragma unroll
  for (int a = 0; a < 2; ++a)
    #pragma unroll
    for (int e = 0; e < 2; ++e) acc[a][e] = (f32x4){0.f, 0.f, 0.f, 0.f};

  const s8v z = {0, 0, 0, 0, 0, 0, 0, 0};
  for (int jj = 0; jj < 4; ++jj) {
    const int j = jg * 4 + jj;
    __syncthreads();
    {
      const short* us = U + (size_t)((b * CC + j) * 200 + oc * 50) * DD;
      const short* ps = PTTb + (size_t)(oc * CC + j) * (OWW * DD) + (size_t)(nq * 50) * DD;
      for (int c = tid; c < 64 * CH; c += 256) {
        int row = c / CH, col = c % CH;
        s8v vu = (row < 50) ? *(const s8v*)(us + (size_t)row * DD + col * 8) : z;
        s8v vp = (row < 50) ? *(const s8v*)(ps + (size_t)row * DD + col * 8) : z;
        *(s8v*)(&ldsU[row * LDP + col * 8]) = vu;
        *(s8v*)(&ldsPT[row * LDP + col * 8]) = vp;
      }
    }
    __syncthreads();

    #pragma unroll
    for (int kc = 0; kc < 6; ++kc) {
      s8v af[2], bf[2];
      #pragma unroll
      for (int a = 0; a < 2; ++a)
        af[a] = *(const s8v*)(&ldsU[((wm2 * 2 + a) * 16 + lane15) * LDP + kc * 32 + quad * 8]);
      #pragma unroll
      for (int e = 0; e < 2; ++e)
        bf[e] = *(const s8v*)(&ldsPT[((wn2 * 2 + e) * 16 + lane15) * LDP + kc * 32 + quad * 8]);
      #pragma unroll
      for (int a = 0; a < 2; ++a)
        #pragma unroll
        for (int e = 0; e < 2; ++e)
          acc[a][e] = __builtin_amdgcn_mfma_f32_16x16x32_bf16(af[a], bf[e], acc[a][e], 0, 0, 0);
    }
  }

  float* dst = out + (size_t)(b * OCC + oc) * (OHH * OWW);
  #pragma unroll
  for (int a = 0; a < 2; ++a) {
    #pragma unroll
    for (int e = 0; e < 2; ++e) {
      int n = (wn2 * 2 + e) * 16 + lane15;
      if (n < 50) {
        #pragma unroll
        for (int r = 0; r < 4; ++r) {
          int m = (wm2 * 2 + a) * 16 + quad * 4 + r;
          if (m < OHH)
            atomicAdd(&dst[(size_t)m * OWW + nq * 50 + n], acc[a][e][r]);
        }
      }
    }
  }
}

// ---------------- launcher ----------------

extern "C" void kernel_launch(void* const* d_in, const int* in_sizes, int n_in,
                              void* d_out, int out_size, void* d_ws, size_t ws_size,
                              hipStream_t stream) {
  const float* x  = (const float*)d_in[0];
  const float* R  = (const float*)d_in[1];
  const float* P  = (const float*)d_in[2];
  const float* PT = (const float*)d_in[3];
  float* out = (float*)d_out;

  short* W = (short*)d_ws;
  const size_t nR    = (size_t)CC * CC * DD * DD;    // 9,437,184
  const size_t nXpad = (size_t)BB * CC * DD * LDP;   // 4,915,200 (padded)
  const size_t nX    = (size_t)BB * CC * DD * DD;    // 4,718,592
  const size_t nP    = (size_t)OCC * CC * OHH * DD;  // 614,400
  const size_t nPT   = (size_t)OCC * CC * OWW * DD;  // 2,457,600
  short* Rb    = W;
  short* XTb   = Rb + nR;
  short* Pb    = XTb + nXpad;
  short* PTTb  = Pb + nP;
  short* ypart = PTTb + nPT;                          // 2 * nX
  short* Ubuf  = ypart + 2 * nX;                      // 128 * 200 * 192

  prep_all<<<PREP_TOTAL, 256, 0, stream>>>(R, Rb, P, Pb, x, XTb, PT, PTTb);
  hipMemsetAsync(d_out, 0, (size_t)out_size * sizeof(float), stream);
  stageA<<<BB * CC * 2, 512, 0, stream>>>(Rb, XTb, ypart);
  stageB1<<<BB * CC * 2, 512, 0, stream>>>(ypart, Pb, Ubuf);
  stageB2<<<BB * OCC * 4 * 4, 256, 0, stream>>>(Ubuf, PTTb, out);
}

// Round 6
// 230.743 us; speedup vs baseline: 1.2147x; 1.0295x over previous
//
#include <hip/hip_runtime.h>
#include <stdint.h>
#include <stddef.h>

// Problem constants
#define BB 8
#define CC 16
#define DD 192
#define OCC 4
#define OHH 50
#define OWW 200

#define LDP 200   // padded LDS row stride in bf16 elements (192 + 8)
#define CH  24    // 8-element chunks per 192 row

typedef __attribute__((ext_vector_type(8))) short s8v;   // 8 bf16 = 16B (MFMA A/B frag)
typedef __attribute__((ext_vector_type(4))) short s4v;   // 4 bf16 = 8B
typedef __attribute__((ext_vector_type(4))) float f4v;   // 4 fp32
typedef __attribute__((ext_vector_type(4))) float f32x4; // MFMA C/D frag

__device__ __forceinline__ short rne_bf16(float f) {
  uint32_t u = __float_as_uint(f);
  u += 0x7fffu + ((u >> 16) & 1u);
  return (short)(u >> 16);
}
__device__ __forceinline__ float bf2f(short s) {
  return __uint_as_float(((uint32_t)(uint16_t)s) << 16);
}

// async 16B-per-lane global->LDS DMA (no VGPR round trip)
__device__ __forceinline__ void async_copy16(short* lds_dst, const short* g_src) {
  __builtin_amdgcn_global_load_lds(
      (const __attribute__((address_space(1))) void*)g_src,
      (__attribute__((address_space(3))) void*)lds_dst, 16, 0, 0);
}

// ---------------- prep_all: R-fragswizzle | P-cvt | x-transpose(padded) | PT-transpose ----------
// Rs layout: frag-tiles of 512 bf16 (1 KB): Rs[ij][mt(12)][kc(6)][lane(64)][8]
//   element (lane,t) = R[ij][mt*16 + (lane&15)][kc*32 + (lane>>4)*8 + t]
// This is exactly the 16x16x32 MFMA B-fragment order -> one coalesced 1KB load per frag.
#define PREP_R_BLK 4608
#define PREP_P_BLK 600
#define PREP_X_BLK 4608
#define PREP_PT_BLK 2688
#define PREP_TOTAL (PREP_R_BLK + PREP_P_BLK + PREP_X_BLK + PREP_PT_BLK)

__global__ __launch_bounds__(256) void prep_all(const float* __restrict__ R, short* __restrict__ Rs,
                                                const float* __restrict__ P, short* __restrict__ Pb,
                                                const float* __restrict__ x, short* __restrict__ XTb,
                                                const float* __restrict__ PT, short* __restrict__ PTTb) {
  __shared__ float tile[32][33];
  const int blk = blockIdx.x;
  const int tid = threadIdx.x;

  if (blk < PREP_R_BLK) {
    int g = blk * 256 + tid;          // one 8-elem frag slice per thread
    int lane = g & 63;
    int fi = g >> 6;
    int kc = fi % 6;
    int mt = (fi / 6) % 12;
    int ij = fi / 72;
    const float* src = R + (size_t)ij * (DD * DD) + (size_t)(mt * 16 + (lane & 15)) * DD
                         + kc * 32 + ((lane >> 4) << 3);
    f4v v0 = *(const f4v*)src;
    f4v v1 = *(const f4v*)(src + 4);
    s8v o;
    #pragma unroll
    for (int r = 0; r < 4; ++r) { o[r] = rne_bf16(v0[r]); o[r + 4] = rne_bf16(v1[r]); }
    *(s8v*)(Rs + (size_t)g * 8) = o;
    return;
  }
  if (blk < PREP_R_BLK + PREP_P_BLK) {
    int idx = (blk - PREP_R_BLK) * 256 + tid;
    f4v v = *(const f4v*)(P + (size_t)idx * 4);
    s4v o;
    #pragma unroll
    for (int r = 0; r < 4; ++r) o[r] = rne_bf16(v[r]);
    *(s4v*)(Pb + (size_t)idx * 4) = o;
    return;
  }
  const int tx = tid & 31, ty = tid >> 5;
  if (blk < PREP_R_BLK + PREP_P_BLK + PREP_X_BLK) {
    // XTb padded: [outer][q][p] with row stride LDP (pad cols garbage, never read)
    int t = blk - (PREP_R_BLK + PREP_P_BLK);
    int outer = t / 36, rem = t % 36;
    int p0 = (rem / 6) * 32, q0 = (rem % 6) * 32;
    const float* src = x + (size_t)outer * DD * DD;
    for (int r = ty; r < 32; r += 8)
      tile[r][tx] = src[(size_t)(p0 + r) * DD + q0 + tx];
    __syncthreads();
    short* dst = XTb + (size_t)outer * DD * LDP;
    for (int r = ty; r < 32; r += 8)
      dst[(size_t)(q0 + r) * LDP + p0 + tx] = rne_bf16(tile[tx][r]);
    return;
  }
  {
    int t = blk - (PREP_R_BLK + PREP_P_BLK + PREP_X_BLK);
    int outer = t / 42, rem = t % 42;
    int q0 = (rem / 7) * 32, n0 = (rem % 7) * 32;
    const float* src = PT + (size_t)outer * DD * OWW;
    for (int r = ty; r < 32; r += 8)
      tile[r][tx] = (n0 + tx < OWW) ? src[(size_t)(q0 + r) * OWW + n0 + tx] : 0.f;
    __syncthreads();
    short* dst = PTTb + (size_t)outer * OWW * DD;
    for (int r = ty; r < 32; r += 8)
      if (n0 + r < OWW) dst[(size_t)(n0 + r) * DD + q0 + tx] = rne_bf16(tile[tx][r]);
  }
}

// ---------------- stage A ----------------
// y[b,i] = sum_j R[i,j] @ x[b,j] @ R[i,j]^T, split over jg halves.
// 1024 threads (16 waves, 4/SIMD). LDS: X (DMA target) + T (separate buffer) -> 2 barriers/j.
// B-operand (R) comes from global via frag-swizzled Rs: one coalesced 1KB load per frag.
// mm1: T^T[q][m] = sum_p X^T[q][p] R[m][p];  mm2: y[m][n] += sum_q T[m][q] R[n][q].
// Same Rs addressing serves both (R-rows free, R-cols contracted).
__global__ __launch_bounds__(1024, 4) void stageA(const short* __restrict__ Rs,
                                                  const short* __restrict__ XTb,
                                                  short* __restrict__ ypart) {
  __shared__ __align__(16) short ldsX[DD * LDP];  // 76.8 KB, DMA target (padded tile)
  __shared__ __align__(16) short ldsT[DD * LDP];  // 76.8 KB
  const int tid = threadIdx.x;
  const int bx = blockIdx.x;
  const int b = bx >> 5, i = (bx >> 1) & 15, jg = bx & 1;
  const int lane15 = tid & 15, quad = (tid & 63) >> 4;
  const int lane = tid & 63;
  const int wid = tid >> 6;   // 0..15
  const int wq = wid >> 2;    // 0..3 : A-operand dim, 3 tiles each
  const int wm = wid & 3;     // 0..3 : B-operand dim, 3 tiles each

  const short* xbase = XTb + (size_t)(b * CC + jg * 8) * (DD * LDP);

  // initial DMA of X^T[j0] (4800 16B chunks, linear copy of padded tile)
  #pragma unroll
  for (int it = 0; it < 5; ++it) {
    int c = tid + it * 1024;
    if (c < DD * LDP / 8) async_copy16(&ldsX[c * 8], xbase + (size_t)c * 8);
  }

  f32x4 acc_y[3][3];
  #pragma unroll
  for (int a = 0; a < 3; ++a)
    #pragma unroll
    for (int c = 0; c < 3; ++c) acc_y[a][c] = (f32x4){0.f, 0.f, 0.f, 0.f};

  for (int jj = 0; jj < 8; ++jj) {
    // frag-tile base for R[i, jg*8+jj]: 72 tiles x 512 elems
    const short* rtile = Rs + (size_t)(i * CC + jg * 8 + jj) * (72 * 512);
    __syncthreads();  // barrier A: X[j] DMA drained; prev mm2 done reading ldsT

    // mm1: T^T[q][m]  (A = ldsX rows q, B = Rs frags m-tile)
    f32x4 acc_t[3][3];
    #pragma unroll
    for (int a = 0; a < 3; ++a)
      #pragma unroll
      for (int c = 0; c < 3; ++c) acc_t[a][c] = (f32x4){0.f, 0.f, 0.f, 0.f};

    #pragma unroll
    for (int kc = 0; kc < 6; ++kc) {
      s8v af[3], bf[3];
      #pragma unroll
      for (int a = 0; a < 3; ++a)
        af[a] = *(const s8v*)(&ldsX[((wq * 3 + a) * 16 + lane15) * LDP + kc * 32 + quad * 8]);
      #pragma unroll
      for (int c = 0; c < 3; ++c)
        bf[c] = *(const s8v*)(rtile + (size_t)(((wm * 3 + c) * 6 + kc) * 512) + lane * 8);
      #pragma unroll
      for (int a = 0; a < 3; ++a)
        #pragma unroll
        for (int c = 0; c < 3; ++c)
          acc_t[a][c] = __builtin_amdgcn_mfma_f32_16x16x32_bf16(af[a], bf[c], acc_t[a][c], 0, 0, 0);
    }

    // pack T[m][q] into ldsT (own buffer; all ldsT readers joined at barrier A)
    #pragma unroll
    for (int a = 0; a < 3; ++a) {
      #pragma unroll
      for (int c = 0; c < 3; ++c) {
        s4v pk;
        #pragma unroll
        for (int r = 0; r < 4; ++r) pk[r] = rne_bf16(acc_t[a][c][r]);
        int m = (wm * 3 + c) * 16 + lane15;
        int q0 = (wq * 3 + a) * 16 + quad * 4;
        *(s4v*)(&ldsT[m * LDP + q0]) = pk;
      }
    }
    __syncthreads();  // barrier B: T complete; all mm1 ldsX reads complete

    // DMA X[j+1] into ldsX, overlapping mm2 (mm2 reads only ldsT + global R)
    if (jj < 7) {
      const short* xn = xbase + (size_t)(jj + 1) * (DD * LDP);
      #pragma unroll
      for (int it = 0; it < 5; ++it) {
        int c = tid + it * 1024;
        if (c < DD * LDP / 8) async_copy16(&ldsX[c * 8], xn + (size_t)c * 8);
      }
    }

    // mm2: y[m][n] += T rows x Rs frags (n-tile, k = q-chunk -> same addressing)
    #pragma unroll
    for (int kc = 0; kc < 6; ++kc) {
      s8v af[3], bf[3];
      #pragma unroll
      for (int a = 0; a < 3; ++a)
        af[a] = *(const s8v*)(&ldsT[((wq * 3 + a) * 16 + lane15) * LDP + kc * 32 + quad * 8]);
      #pragma unroll
      for (int c = 0; c < 3; ++c)
        bf[c] = *(const s8v*)(rtile + (size_t)(((wm * 3 + c) * 6 + kc) * 512) + lane * 8);
      #pragma unroll
      for (int a = 0; a < 3; ++a)
        #pragma unroll
        for (int c = 0; c < 3; ++c)
          acc_y[a][c] = __builtin_amdgcn_mfma_f32_16x16x32_bf16(af[a], bf[c], acc_y[a][c], 0, 0, 0);
    }
  }

  // pack y^T [n][m] into ldsX (last DMA already consumed; mm2 read only ldsT)
  __syncthreads();
  #pragma unroll
  for (int a = 0; a < 3; ++a) {
    #pragma unroll
    for (int c = 0; c < 3; ++c) {
      s4v pk;
      #pragma unroll
      for (int r = 0; r < 4; ++r) pk[r] = rne_bf16(acc_y[a][c][r]);
      int n = (wm * 3 + c) * 16 + lane15;    // y col
      int m0 = (wq * 3 + a) * 16 + quad * 4; // y row, 4 consecutive
      *(s4v*)(&ldsX[n * LDP + m0]) = pk;
    }
  }
  __syncthreads();
  {
    short* dst = ypart + (size_t)(jg * (BB * CC) + b * CC + i) * (DD * DD);
    #pragma unroll
    for (int it = 0; it < 5; ++it) {
      int c = tid + it * 1024;
      if (c < DD * CH)
        *(s8v*)(dst + (size_t)c * 8) = *(const s8v*)(&ldsX[(c / CH) * LDP + (c % CH) * 8]);
    }
  }
}

// ---------------- stage B1 ----------------
// U[b,j][m_cat][q] = sum_p P_cat[m_cat][p] y[b,j][p][q], split over q-halves.
__global__ __launch_bounds__(512, 1) void stageB1(const short* __restrict__ ypart,
                                                  const short* __restrict__ Pb,
                                                  short* __restrict__ U) {
  __shared__ __align__(16) short ldsYT[96 * LDP];
  __shared__ __align__(16) short ldsP[208 * LDP];
  const int tid = threadIdx.x;
  const int bx = blockIdx.x;
  const int qh = bx & 1, j = (bx >> 1) & 15, b = bx >> 5;
  const int lane15 = tid & 15, quad = (tid & 63) >> 4;
  const int wid = tid >> 6;
  const int wq1 = wid >> 2;
  const int wm1 = wid & 3;

  {
    const short* p0 = ypart + (size_t)(b * CC + j) * (DD * DD) + (size_t)(qh * 96) * DD;
    const short* p1 = p0 + (size_t)(BB * CC) * (DD * DD);
    for (int c = tid; c < 96 * CH; c += 512) {
      s8v v0 = *(const s8v*)(p0 + (size_t)c * 8);
      s8v v1 = *(const s8v*)(p1 + (size_t)c * 8);
      s8v o;
      #pragma unroll
      for (int r = 0; r < 8; ++r) o[r] = rne_bf16(bf2f(v0[r]) + bf2f(v1[r]));
      *(s8v*)(&ldsYT[(c / CH) * LDP + (c % CH) * 8]) = o;
    }
    const s8v z = {0, 0, 0, 0, 0, 0, 0, 0};
    for (int c = tid; c < 208 * CH; c += 512) {
      int row = c / CH, col = c % CH;
      s8v v = z;
      if (row < 200) {
        int oc = row / 50, m = row - oc * 50;
        v = *(const s8v*)(Pb + (size_t)(oc * CC + j) * (OHH * DD) + (size_t)m * DD + col * 8);
      }
      *(s8v*)(&ldsP[row * LDP + col * 8]) = v;
    }
  }
  __syncthreads();

  f32x4 acc[3][4];
  #pragma unroll
  for (int a = 0; a < 3; ++a)
    #pragma unroll
    for (int e = 0; e < 4; ++e) acc[a][e] = (f32x4){0.f, 0.f, 0.f, 0.f};

  #pragma unroll
  for (int kc = 0; kc < 6; ++kc) {
    s8v af[3], bf[4];
    #pragma unroll
    for (int a = 0; a < 3; ++a)
      af[a] = *(const s8v*)(&ldsYT[((wq1 * 3 + a) * 16 + lane15) * LDP + kc * 32 + quad * 8]);
    #pragma unroll
    for (int e = 0; e < 4; ++e) {
      int tn = wm1 * 4 + e;
      if (tn < 13)
        bf[e] = *(const s8v*)(&ldsP[(tn * 16 + lane15) * LDP + kc * 32 + quad * 8]);
    }
    #pragma unroll
    for (int a = 0; a < 3; ++a)
      #pragma unroll
      for (int e = 0; e < 4; ++e)
        if (wm1 * 4 + e < 13)
          acc[a][e] = __builtin_amdgcn_mfma_f32_16x16x32_bf16(af[a], bf[e], acc[a][e], 0, 0, 0);
  }

  short* ub = U + (size_t)(b * CC + j) * (200 * DD);
  #pragma unroll
  for (int a = 0; a < 3; ++a) {
    #pragma unroll
    for (int e = 0; e < 4; ++e) {
      int tn = wm1 * 4 + e;
      if (tn < 13) {
        int m = tn * 16 + lane15;
        if (m < 200) {
          s4v pk;
          #pragma unroll
          for (int r = 0; r < 4; ++r) pk[r] = rne_bf16(acc[a][e][r]);
          int q0 = qh * 96 + (wq1 * 3 + a) * 16 + quad * 4;
          *(s4v*)(ub + (size_t)m * DD + q0) = pk;
        }
      }
    }
  }
}

// ---------------- stage B2 ----------------
__global__ __launch_bounds__(256, 2) void stageB2(const short* __restrict__ U,
                                                  const short* __restrict__ PTTb,
                                                  float* __restrict__ out) {
  __shared__ __align__(16) short ldsU[64 * LDP];
  __shared__ __align__(16) short ldsPT[64 * LDP];
  const int tid = threadIdx.x;
  const int bx = blockIdx.x;
  const int jg = bx & 3, nq = (bx >> 2) & 3, oc = (bx >> 4) & 3, b = bx >> 6;
  const int lane15 = tid & 15, quad = (tid & 63) >> 4;
  const int wid = tid >> 6;
  const int wm2 = wid & 1, wn2 = wid >> 1;

  f32x4 acc[2][2];
  #pragma unroll
  for (int a = 0; a < 2; ++a)
    #pragma unroll
    for (int e = 0; e < 2; ++e) acc[a][e] = (f32x4){0.f, 0.f, 0.f, 0.f};

  const s8v z = {0, 0, 0, 0, 0, 0, 0, 0};
  for (int jj = 0; jj < 4; ++jj) {
    const int j = jg * 4 + jj;
    __syncthreads();
    {
      const short* us = U + (size_t)((b * CC + j) * 200 + oc * 50) * DD;
      const short* ps = PTTb + (size_t)(oc * CC + j) * (OWW * DD) + (size_t)(nq * 50) * DD;
      for (int c = tid; c < 64 * CH; c += 256) {
        int row = c / CH, col = c % CH;
        s8v vu = (row < 50) ? *(const s8v*)(us + (size_t)row * DD + col * 8) : z;
        s8v vp = (row < 50) ? *(const s8v*)(ps + (size_t)row * DD + col * 8) : z;
        *(s8v*)(&ldsU[row * LDP + col * 8]) = vu;
        *(s8v*)(&ldsPT[row * LDP + col * 8]) = vp;
      }
    }
    __syncthreads();

    #pragma unroll
    for (int kc = 0; kc < 6; ++kc) {
      s8v af[2], bf[2];
      #pragma unroll
      for (int a = 0; a < 2; ++a)
        af[a] = *(const s8v*)(&ldsU[((wm2 * 2 + a) * 16 + lane15) * LDP + kc * 32 + quad * 8]);
      #pragma unroll
      for (int e = 0; e < 2; ++e)
        bf[e] = *(const s8v*)(&ldsPT[((wn2 * 2 + e) * 16 + lane15) * LDP + kc * 32 + quad * 8]);
      #pragma unroll
      for (int a = 0; a < 2; ++a)
        #pragma unroll
        for (int e = 0; e < 2; ++e)
          acc[a][e] = __builtin_amdgcn_mfma_f32_16x16x32_bf16(af[a], bf[e], acc[a][e], 0, 0, 0);
    }
  }

  float* dst = out + (size_t)(b * OCC + oc) * (OHH * OWW);
  #pragma unroll
  for (int a = 0; a < 2; ++a) {
    #pragma unroll
    for (int e = 0; e < 2; ++e) {
      int n = (wn2 * 2 + e) * 16 + lane15;
      if (n < 50) {
        #pragma unroll
        for (int r = 0; r < 4; ++r) {
          int m = (wm2 * 2 + a) * 16 + quad * 4 + r;
          if (m < OHH)
            atomicAdd(&dst[(size_t)m * OWW + nq * 50 + n], acc[a][e][r]);
        }
      }
    }
  }
}

// ---------------- launcher ----------------

extern "C" void kernel_launch(void* const* d_in, const int* in_sizes, int n_in,
                              void* d_out, int out_size, void* d_ws, size_t ws_size,
                              hipStream_t stream) {
  const float* x  = (const float*)d_in[0];
  const float* R  = (const float*)d_in[1];
  const float* P  = (const float*)d_in[2];
  const float* PT = (const float*)d_in[3];
  float* out = (float*)d_out;

  short* W = (short*)d_ws;
  const size_t nR    = (size_t)CC * CC * DD * DD;    // 9,437,184
  const size_t nXpad = (size_t)BB * CC * DD * LDP;   // 4,915,200 (padded)
  const size_t nX    = (size_t)BB * CC * DD * DD;    // 4,718,592
  const size_t nP    = (size_t)OCC * CC * OHH * DD;  // 614,400
  const size_t nPT   = (size_t)OCC * CC * OWW * DD;  // 2,457,600
  short* Rs    = W;
  short* XTb   = Rs + nR;
  short* Pb    = XTb + nXpad;
  short* PTTb  = Pb + nP;
  short* ypart = PTTb + nPT;                          // 2 * nX
  short* Ubuf  = ypart + 2 * nX;                      // 128 * 200 * 192

  prep_all<<<PREP_TOTAL, 256, 0, stream>>>(R, Rs, P, Pb, x, XTb, PT, PTTb);
  hipMemsetAsync(d_out, 0, (size_t)out_size * sizeof(float), stream);
  stageA<<<BB * CC * 2, 1024, 0, stream>>>(Rs, XTb, ypart);
  stageB1<<<BB * CC * 2, 512, 0, stream>>>(ypart, Pb, Ubuf);
  stageB2<<<BB * OCC * 4 * 4, 256, 0, stream>>>(Ubuf, PTTb, out);
}